// Round 16
// baseline (71.284 us; speedup 1.0000x reference)
//
#include <hip/hip_runtime.h>
#include <hip/hip_bf16.h>

// MeanAggregator: out[b,:] = mean over UNIQUE neigh_idx[b,:] of embed[idx,:]
// B=2048, K=32, N=50000, D=128 (f32)
//
// Round-10 post-mortem: kernel ~26us (dur_us 69.9 minus the harness's 43.4us
// 256MiB ws re-poison fill visible in rocprof), vs 6-12 predicted. Cause:
// 1 wave/row = 8 waves/CU (2/SIMD) -> gather latency (~600-900cy L2/L3/HBM)
// almost unhidden. Fix: 4 waves/row, 256-thread blocks, grid=2048 ->
// 32 waves/CU (full occupancy), 4 loads/thread instead of 16.
//
// - Lanes 0-31 (wave 0): load ids (coalesced 128B), dedupe via 31 __shfl
//   broadcasts in-register; weight 0 for dups (expected dups/row = K^2/2N
//   ~ 0.01 -> compaction is strictly a loss); publish off/w via LDS.
// - Thread t: chunk = t&31 (16B float4 of a row), g = t>>5 (0..7).
//   Rows r = 8k+g, k=0..3: 4 independent unrolled 1KiB wave-loads.
//   s_w/s_off reads are 2-way LDS broadcasts (free).
// - Reduce: __shfl_xor(.,32) folds g-parity inside each wave; waves 1-3
//   deposit 32 float4 each in LDS (1.5KB); wave 0 lanes 0-31 sum, scale
//   by 1/#unique, store 512B coalesced.

#define KNEIGH 32
#define DIM 128

__global__ __launch_bounds__(256) void mean_agg_kernel(
    const float* __restrict__ embed,
    const int* __restrict__ neigh_idx,
    float* __restrict__ out)
{
    __shared__ int    s_off[KNEIGH];   // element offsets idx*DIM (max 6.4e6)
    __shared__ float  s_w[KNEIGH];     // 1.0 first occurrence, 0.0 dup
    __shared__ float  s_inv;           // 1 / #unique
    __shared__ float4 s_part[3][32];   // waves 1..3 partials (1.5KB)

    const int b = blockIdx.x;
    const int t = threadIdx.x;

    if (t < KNEIGH) {
        const int v = neigh_idx[b * KNEIGH + t];   // coalesced 128B
        int dup = 0;
        #pragma unroll
        for (int j = 0; j < KNEIGH - 1; ++j) {
            const int vj = __shfl(v, j);           // in-register broadcast
            dup |= (j < t) & (vj == v);
        }
        s_off[t] = v * DIM;
        s_w[t]   = dup ? 0.0f : 1.0f;
        const unsigned long long m = __ballot(!dup);  // lanes 0-31 active
        if (t == 0) s_inv = 1.0f / (float)__popcll(m & 0xffffffffull);
    }
    __syncthreads();

    const int chunk = t & 31;   // 16B float4 chunk within row
    const int g     = t >> 5;   // row group 0..7

    float4 acc = make_float4(0.f, 0.f, 0.f, 0.f);
    #pragma unroll
    for (int k = 0; k < 4; ++k) {
        const int   r   = 8 * k + g;
        const float w   = s_w[r];                    // 2-way LDS broadcast
        const int   off = s_off[r];
        const float4 v  = *reinterpret_cast<const float4*>(
            embed + off + (chunk << 2));             // 16B-aligned 1KiB/wave
        acc.x = fmaf(w, v.x, acc.x);
        acc.y = fmaf(w, v.y, acc.y);
        acc.z = fmaf(w, v.z, acc.z);
        acc.w = fmaf(w, v.w, acc.w);
    }

    // fold odd/even g within the wave (lanes t^32 hold the sibling group)
    acc.x += __shfl_xor(acc.x, 32);
    acc.y += __shfl_xor(acc.y, 32);
    acc.z += __shfl_xor(acc.z, 32);
    acc.w += __shfl_xor(acc.w, 32);

    const int wv = t >> 6;      // wave id 0..3
    if (wv > 0 && (t & 63) < 32) {
        s_part[wv - 1][chunk] = acc;
    }
    __syncthreads();

    if (t < 32) {
        const float4 p0 = s_part[0][t];
        const float4 p1 = s_part[1][t];
        const float4 p2 = s_part[2][t];
        const float  inv = s_inv;
        float4 r;
        r.x = ((acc.x + p0.x) + (p1.x + p2.x)) * inv;
        r.y = ((acc.y + p0.y) + (p1.y + p2.y)) * inv;
        r.z = ((acc.z + p0.z) + (p1.z + p2.z)) * inv;
        r.w = ((acc.w + p0.w) + (p1.w + p2.w)) * inv;
        *reinterpret_cast<float4*>(out + b * DIM + (t << 2)) = r;
    }
}

extern "C" void kernel_launch(void* const* d_in, const int* in_sizes, int n_in,
                              void* d_out, int out_size, void* d_ws, size_t ws_size,
                              hipStream_t stream) {
    const float* embed     = (const float*)d_in[0];
    const int*   neigh_idx = (const int*)d_in[1];
    float*       out       = (float*)d_out;

    const int B = in_sizes[1] / KNEIGH;  // 2048

    mean_agg_kernel<<<B, 256, 0, stream>>>(embed, neigh_idx, out);
}